// Round 6
// baseline (277.872 us; speedup 1.0000x reference)
//
#include <hip/hip_runtime.h>
#include <cstdint>

#define BB 64
#define PP 8732
#define CC 81
#define PRB 128            // priors per block in k_rowstats
#define TPB 512            // threads per block (4 threads/prior)
#define NBX ((PP + PRB - 1) / PRB)   // 69 blocks per batch row

#define GLOBAL_AS __attribute__((address_space(1)))
#define LDS_AS __attribute__((address_space(3)))

// ---------- wave (64-lane) reductions ----------
__device__ __forceinline__ float wsum(float v) {
#pragma unroll
  for (int o = 32; o > 0; o >>= 1) v += __shfl_xor(v, o, 64);
  return v;
}
__device__ __forceinline__ int wsumi(int v) {
#pragma unroll
  for (int o = 32; o > 0; o >>= 1) v += __shfl_xor(v, o, 64);
  return v;
}

// ---------- kernel 1: per-prior log-softmax stats, 4 threads per prior ----------
// PRB=128/TPB=512: halves the block count (8768->4416) to amortize per-block
// fixed costs (dispatch, prefetch issue, barrier drain, retirement), which
// R3-R5 evidence says dominate (VALUBusy 14% at 58% occupancy; async-DMA
// staging change was neutral). LDS 41.5 KB -> 3 blocks x 8 waves = 24 w/CU.
__global__ __launch_bounds__(TPB) void k_rowstats(
    const float* __restrict__ conf, const float* __restrict__ ploc,
    const int* __restrict__ label, const float* __restrict__ gloc,
    float* __restrict__ negp, int* __restrict__ part_cnt,
    float* __restrict__ part_nll, float* __restrict__ part_loc) {
  __shared__ float s_lin[PRB * CC];       // 41472 B
  __shared__ float sh_n[TPB / 64], sh_l[TPB / 64];
  __shared__ int sh_c[TPB / 64];

  const int b = blockIdx.y;
  const int bx = blockIdx.x;
  const int p0 = bx * PRB;
  const int np = min(PRB, PP - p0);       // 128 or 28 (both %4==0)
  const int tid = threadIdx.x;
  const size_t rowbase = (size_t)b * PP + p0;
  const size_t gbase = rowbase * CC;      // multiple of 4 -> 16B aligned

  // ---- async DMA stage: global -> LDS, 16 B per lane, linear layout ----
  {
    const GLOBAL_AS float* g = (const GLOBAL_AS float*)(conf + gbase);
    LDS_AS float* l = (LDS_AS float*)s_lin;
    const int n4 = (np * CC) >> 2;        // 2592 or 567
    for (int i = tid; i < n4; i += TPB)
      __builtin_amdgcn_global_load_lds((const GLOBAL_AS void*)(g + 4 * i),
                                       (LDS_AS void*)(l + 4 * i), 16, 0, 0);
  }

  // ---- independent loads issued while the DMA is in flight ----
  const int p = tid >> 2, q = tid & 3;
  const bool act = (p < np);
  int lab = 0;
  float df = 0.0f;
  if (act) {
    lab = label[rowbase + p];             // 4 lanes same addr -> broadcast
    const size_t idx = rowbase * 4 + tid; // == (rowbase+p)*4 + q, coalesced
    df = ploc[idx] - gloc[idx];
  }
  __syncthreads();                        // drains the DMA + barrier

  float nll_acc = 0.0f, loc_acc = 0.0f;
  int cnt = 0;
  if (act) {
    const float* xr = s_lin + p * CC;
    float s = 0.0f;
    for (int c = q; c < CC; c += 4) s += __expf(xr[c]);
    s += __shfl_xor(s, 1, 64);
    s += __shfl_xor(s, 2, 64);            // all 4 lanes hold full sum
    const float lse = __logf(s);

    const bool pos = lab > 0;
    const float ad = fabsf(df);
    loc_acc = pos ? ((ad < 1.0f) ? 0.5f * df * df : ad - 0.5f) : 0.0f;
    if (q == 0) {
      negp[rowbase + p] = pos ? 0.0f : fmaxf(lse - xr[0], 0.0f);
      if (pos) { cnt = 1; nll_acc = lse - xr[lab]; }
    }
  }

  // ---- block reduce -> one plain store per block (no atomics) ----
  const float na = wsum(nll_acc);
  const float la = wsum(loc_acc);
  const int ca = wsumi(cnt);
  const int wave = tid >> 6, lane = tid & 63;
  if (lane == 0) { sh_n[wave] = na; sh_l[wave] = la; sh_c[wave] = ca; }
  __syncthreads();
  if (tid == 0) {
    float tn = 0.0f, tl = 0.0f; int tc = 0;
#pragma unroll
    for (int w = 0; w < TPB / 64; ++w) { tn += sh_n[w]; tl += sh_l[w]; tc += sh_c[w]; }
    const int slot = b * NBX + bx;
    part_cnt[slot] = tc;
    part_nll[slot] = tn;
    part_loc[slot] = tl;
  }
}

// ---------- kernel 2: reduce partials + per-row top-K via radix select ----------
#define RREP 16
#define HSTR 257
#define TTK 1024
__global__ __launch_bounds__(TTK) void k_topk(
    const float* __restrict__ negp, const int* __restrict__ part_cnt,
    const float* __restrict__ part_nll, const float* __restrict__ part_loc,
    int* __restrict__ row_npos, float* __restrict__ row_nll,
    float* __restrict__ row_loc, float* __restrict__ row_topk) {
  __shared__ uint32_t s_v[PP];            // 34928 B
  __shared__ int s_hist[RREP * HSTR];     // 16448 B
  __shared__ int s_tot[256];
  __shared__ uint32_t s_pref;
  __shared__ int s_kk;
  __shared__ int s_npos;
  __shared__ float s_redn[TTK / 64], s_redl[TTK / 64], s_redf[TTK / 64];
  __shared__ int s_redc[TTK / 64];

  const int b = blockIdx.x;
  const int tid = threadIdx.x;
  const int lane = tid & 63, wave = tid >> 6;

  // ---- async DMA stage of the 8732 values (PP = 2183*4, base 16B-aligned)
  {
    const GLOBAL_AS float* g = (const GLOBAL_AS float*)(negp + (size_t)b * PP);
    LDS_AS uint32_t* l = (LDS_AS uint32_t*)s_v;
    for (int i = tid; i < PP / 4; i += TTK)
      __builtin_amdgcn_global_load_lds((const GLOBAL_AS void*)(g + 4 * i),
                                       (LDS_AS void*)(l + 4 * i), 16, 0, 0);
  }

  // ---- overlap: reduce this row's 69 partials + clear pass-0 histogram ----
  {
    int c = 0; float n = 0.0f, l = 0.0f;
    if (tid < NBX) {
      const int slot = b * NBX + tid;
      c = part_cnt[slot]; n = part_nll[slot]; l = part_loc[slot];
    }
    const int cc = wsumi(c);
    const float nn = wsum(n);
    const float ll = wsum(l);
    if (lane == 0) { s_redc[wave] = cc; s_redn[wave] = nn; s_redl[wave] = ll; }
  }
  for (int i = tid; i < RREP * HSTR; i += TTK) s_hist[i] = 0;
  __syncthreads();
  if (tid == 0) {
    int tc = 0; float tn = 0.0f, tl = 0.0f;
#pragma unroll
    for (int w = 0; w < TTK / 64; ++w) { tc += s_redc[w]; tn += s_redn[w]; tl += s_redl[w]; }
    row_npos[b] = tc; row_nll[b] = tn; row_loc[b] = tl;
    s_npos = tc;
  }
  __syncthreads();

  const int npos = s_npos;
  int K = 3 * npos;
  const int mx = PP - npos;
  if (K > mx) K = mx;
  if (K <= 0) {                           // block-uniform branch
    if (tid == 0) row_topk[b] = 0.0f;
    return;
  }

  if (tid == 0) { s_pref = 0u; s_kk = K; }
  __syncthreads();
  const int rep = tid & (RREP - 1);

  for (int pass = 0; pass < 4; ++pass) {
    const int sh = 24 - 8 * pass;
    const uint32_t himask = (pass == 0) ? 0u : (0xFFFFFFFFu << (sh + 8));
    const uint32_t pref = s_pref;
    for (int i = tid; i < PP; i += TTK) {
      const uint32_t u = s_v[i];
      if ((u & himask) == (pref & himask))
        atomicAdd(&s_hist[rep * HSTR + ((u >> sh) & 0xFF)], 1);
    }
    __syncthreads();
    if (tid < 256) {
      int tt = 0;
#pragma unroll
      for (int r = 0; r < RREP; ++r) tt += s_hist[r * HSTR + tid];
      s_tot[tid] = tt;
    }
    __syncthreads();
    // clear histogram for next pass while wave 0 finds the threshold bin
    for (int i = tid; i < RREP * HSTR; i += TTK) s_hist[i] = 0;
    // wave-0 parallel suffix-scan: find bin B with S(B) >= kk > S(B+1)
    if (tid < 64) {
      const int l = tid;
      const int e0 = s_tot[4 * l], e1 = s_tot[4 * l + 1];
      const int e2 = s_tot[4 * l + 2], e3 = s_tot[4 * l + 3];
      const int L = e0 + e1 + e2 + e3;
      int x = L;                          // inclusive suffix over lane totals
#pragma unroll
      for (int o = 1; o < 64; o <<= 1) {
        const int v = __shfl_down(x, o, 64);
        if (l + o < 64) x += v;
      }
      const int T = x - L;                // sum over lanes > l
      const int S3 = e3 + T, S2 = e2 + S3, S1 = e1 + S2, S0 = e0 + S1;
      const int kk = s_kk;
      const uint32_t pf = s_pref;
      if (S0 >= kk && S1 < kk) { s_pref = pf | ((uint32_t)(4 * l + 0) << sh); s_kk = kk - S1; }
      if (S1 >= kk && S2 < kk) { s_pref = pf | ((uint32_t)(4 * l + 1) << sh); s_kk = kk - S2; }
      if (S2 >= kk && S3 < kk) { s_pref = pf | ((uint32_t)(4 * l + 2) << sh); s_kk = kk - S3; }
      if (S3 >= kk && T  < kk) { s_pref = pf | ((uint32_t)(4 * l + 3) << sh); s_kk = kk - T; }
    }
    __syncthreads();
  }

  const uint32_t T = s_pref;
  const int kk = s_kk;
  float local = 0.0f;
  for (int i = tid; i < PP; i += TTK) {
    const uint32_t u = s_v[i];
    if (u > T) local += __uint_as_float(u);
  }
  local = wsum(local);
  if (lane == 0) s_redf[wave] = local;
  __syncthreads();
  if (tid == 0) {
    float tot = 0.0f;
#pragma unroll
    for (int w = 0; w < TTK / 64; ++w) tot += s_redf[w];
    row_topk[b] = tot + (float)kk * __uint_as_float(T);
  }
}

// ---------- kernel 3: finalize (one wave handles all 64 rows) ----------
__global__ void k_final(const int* __restrict__ row_npos, const float* __restrict__ row_nll,
                        const float* __restrict__ row_loc, const float* __restrict__ row_topk,
                        float* __restrict__ out) {
  const int lane = threadIdx.x;   // 64 threads
  const int npos = row_npos[lane];
  const float nll = row_nll[lane] + row_topk[lane];
  const float loc = row_loc[lane];
  int K = 3 * npos;
  const int mx = PP - npos;
  if (K > mx) K = mx;
  const float nsel = (float)(npos + K);

  const float tot_nll = wsum(nll);
  const float tot_loc = wsum(loc);
  const float tot_pos = wsum((float)npos);
  const float tot_sel = wsum(nsel);

  const float ce = tot_nll / fmaxf(tot_sel, 1.0f);
  out[lane] = ce / (float)npos;                      // conf_loss (B,1)
  if (lane == 0) out[BB] = tot_loc / fmaxf(tot_pos, 1.0f);  // loc_huber_loss
}

extern "C" void kernel_launch(void* const* d_in, const int* in_sizes, int n_in,
                              void* d_out, int out_size, void* d_ws, size_t ws_size,
                              hipStream_t stream) {
  const float* conf = (const float*)d_in[0];
  const float* ploc = (const float*)d_in[1];
  const int* label = (const int*)d_in[2];
  const float* gloc = (const float*)d_in[3];
  float* out = (float*)d_out;

  float* negp = (float*)d_ws;                          // BB*PP floats
  int* part_cnt = (int*)(negp + (size_t)BB * PP);      // BB*NBX ints
  float* part_nll = (float*)(part_cnt + BB * NBX);     // BB*NBX floats
  float* part_loc = part_nll + BB * NBX;               // BB*NBX floats
  int* row_npos = (int*)(part_loc + BB * NBX);         // BB ints
  float* row_nll = (float*)(row_npos + BB);            // BB floats
  float* row_loc = row_nll + BB;                       // BB floats
  float* row_topk = row_loc + BB;                      // BB floats

  dim3 g1(NBX, BB);                                    // (69, 64)
  hipLaunchKernelGGL(k_rowstats, g1, dim3(TPB), 0, stream,
                     conf, ploc, label, gloc, negp, part_cnt, part_nll, part_loc);
  hipLaunchKernelGGL(k_topk, dim3(BB), dim3(TTK), 0, stream,
                     negp, part_cnt, part_nll, part_loc,
                     row_npos, row_nll, row_loc, row_topk);
  hipLaunchKernelGGL(k_final, dim3(1), dim3(64), 0, stream,
                     row_npos, row_nll, row_loc, row_topk, out);
}